// Round 1
// baseline (79.695 us; speedup 1.0000x reference)
//
#include <hip/hip_runtime.h>

#define BATCH 16
#define NPTS 4096

// Kernel 1: one block per (batch, 256-wide n-chunk). Stage all 4096 points of
// the batch in LDS as float4(x,y,z,|p|^2). Each thread owns one n, computes
// min_m (|p_m|^2 - 2 * (M p_n) . p_m), adds |p_n|^2, block-reduces the sum of
// the 256 min-distances, writes one partial sum per block.
__global__ __launch_bounds__(256) void chamfer_sym_kernel(
    const float* __restrict__ xyz, float* __restrict__ partial) {
    __shared__ float4 pts[NPTS];           // 64 KB
    __shared__ float red[4];

    const int b = blockIdx.x >> 4;         // 16 n-chunks per batch
    const int nchunk = blockIdx.x & 15;
    const float* base = xyz + (size_t)b * 3 * NPTS;

    // Stage: coalesced planar reads (x, y, z planes), compute |p|^2 on the fly.
    for (int i = threadIdx.x; i < NPTS; i += 256) {
        float x = base[i];
        float y = base[NPTS + i];
        float z = base[2 * NPTS + i];
        pts[i] = make_float4(x, y, z, x * x + y * y + z * z);
    }
    __syncthreads();

    const int n = (nchunk << 8) + threadIdx.x;
    float4 pn = pts[n];
    const float ax = -pn.x;                // mirrored point (yz-plane: negate x)
    const float ay = pn.y;
    const float az = pn.z;
    const float a2 = pn.w;                 // |M p_n|^2 == |p_n|^2

    float bestv[8];
#pragma unroll
    for (int j = 0; j < 8; ++j) bestv[j] = 1e30f;

    for (int m = 0; m < NPTS; m += 8) {
#pragma unroll
        for (int j = 0; j < 8; ++j) {
            float4 p = pts[m + j];         // wave-uniform address -> broadcast
            float ab = fmaf(ax, p.x, fmaf(ay, p.y, az * p.z));
            bestv[j] = fminf(bestv[j], fmaf(-2.0f, ab, p.w));
        }
    }

    float best = fminf(fminf(fminf(bestv[0], bestv[1]), fminf(bestv[2], bestv[3])),
                       fminf(fminf(bestv[4], bestv[5]), fminf(bestv[6], bestv[7])));
    float dist = a2 + best;                // min_m |M p_n - p_m|^2

    // Block-reduce sum over 256 threads (4 waves of 64).
    float sum = dist;
#pragma unroll
    for (int off = 32; off; off >>= 1) sum += __shfl_down(sum, off, 64);
    if ((threadIdx.x & 63) == 0) red[threadIdx.x >> 6] = sum;
    __syncthreads();
    if (threadIdx.x == 0)
        partial[blockIdx.x] = (red[0] + red[1]) + (red[2] + red[3]);
}

// Kernel 2: reduce the 256 block partials, scale, write scalar loss.
__global__ __launch_bounds__(256) void reduce_kernel(
    const float* __restrict__ partial, float* __restrict__ out) {
    __shared__ float red[4];
    float v = partial[threadIdx.x];
#pragma unroll
    for (int off = 32; off; off >>= 1) v += __shfl_down(v, off, 64);
    if ((threadIdx.x & 63) == 0) red[threadIdx.x >> 6] = v;
    __syncthreads();
    if (threadIdx.x == 0) {
        float total = (red[0] + red[1]) + (red[2] + red[3]);
        // loss = mean_b(mean12 + mean21) = 2/(B*N) * sum of mins
        out[0] = total * (2.0f / (float)(BATCH * NPTS));
    }
}

extern "C" void kernel_launch(void* const* d_in, const int* in_sizes, int n_in,
                              void* d_out, int out_size, void* d_ws, size_t ws_size,
                              hipStream_t stream) {
    const float* xyz = (const float*)d_in[0];
    float* out = (float*)d_out;
    float* partial = (float*)d_ws;   // 256 floats

    chamfer_sym_kernel<<<BATCH * 16, 256, 0, stream>>>(xyz, partial);
    reduce_kernel<<<1, 256, 0, stream>>>(partial, out);
}

// Round 2
// 32.772 us; speedup vs baseline: 2.4318x; 2.4318x over previous
//
#include <hip/hip_runtime.h>

#define BATCH 16
#define NPTS 4096
#define TOTN (BATCH * NPTS)   // 65536

// Pass 1: blocks = BATCH * 2 * S, where S = NPTS / MC m-chunks.
// Each block: one batch b, one 2048-wide n-group, one MC-wide m-chunk.
// Stage q_m = (-2x, -2y, -2z, |p_m|^2) for the m-chunk in LDS.
// Each of 256 threads owns 8 n's (strided by 256 within the n-group) and
// computes partial_min_m [ q_m . a_n + q_m.w ] where a_n = (-x_n, y_n, z_n).
// Writes per-(m-chunk, n) partial mins to ws (coalesced).
template <int MC>
__global__ __launch_bounds__(256) void chamfer_part_kernel(
    const float* __restrict__ xyz, float* __restrict__ partial) {
    constexpr int S = NPTS / MC;
    __shared__ float4 q[MC];

    const int bid = blockIdx.x;
    const int s = bid % S;
    const int ng = (bid / S) & 1;
    const int b = bid / (2 * S);
    const float* base = xyz + (size_t)b * 3 * NPTS;

    // Stage m-chunk as q = (-2x, -2y, -2z, |p|^2)
    const int m0 = s * MC;
    for (int i = threadIdx.x; i < MC; i += 256) {
        float x = base[m0 + i];
        float y = base[NPTS + m0 + i];
        float z = base[2 * NPTS + m0 + i];
        q[i] = make_float4(-2.0f * x, -2.0f * y, -2.0f * z,
                           x * x + y * y + z * z);
    }
    __syncthreads();

    // Load this thread's 8 mirrored n-points (coalesced per j).
    const int nbase = ng * 2048 + threadIdx.x;
    float ax[8], ay[8], az[8], acc[8];
#pragma unroll
    for (int j = 0; j < 8; ++j) {
        int n = nbase + j * 256;
        ax[j] = -base[n];              // mirror across yz-plane
        ay[j] = base[NPTS + n];
        az[j] = base[2 * NPTS + n];
        acc[j] = 1e30f;
    }

    // Main loop: per m, 1 broadcast LDS read feeds 8 n's (4 ops each).
    for (int m = 0; m < MC; m += 4) {
#pragma unroll
        for (int u = 0; u < 4; ++u) {
            float4 p = q[m + u];
#pragma unroll
            for (int j = 0; j < 8; ++j) {
                float t = fmaf(p.x, ax[j],
                          fmaf(p.y, ay[j],
                          fmaf(p.z, az[j], p.w)));
                acc[j] = fminf(acc[j], t);
            }
        }
    }

    // partial[s][global_n], coalesced stores per j.
    float* dst = partial + (size_t)s * TOTN + b * NPTS + ng * 2048 + threadIdx.x;
#pragma unroll
    for (int j = 0; j < 8; ++j) dst[j * 256] = acc[j];
}

// Pass 2: per n, min over S chunks, add |p_n|^2, block-sum 256 n's.
__global__ __launch_bounds__(256) void combine_kernel(
    const float* __restrict__ xyz, const float* __restrict__ partial,
    float* __restrict__ blocksums, int S) {
    __shared__ float red[4];
    const int n = blockIdx.x * 256 + threadIdx.x;   // 0..TOTN-1
    const int b = n >> 12;
    const int i = n & (NPTS - 1);
    const float* base = xyz + (size_t)b * 3 * NPTS;
    float x = base[i], y = base[NPTS + i], z = base[2 * NPTS + i];

    float v = 1e30f;
    for (int s = 0; s < S; ++s) v = fminf(v, partial[(size_t)s * TOTN + n]);
    float sum = x * x + y * y + z * z + v;   // min_m |M p_n - p_m|^2

#pragma unroll
    for (int off = 32; off; off >>= 1) sum += __shfl_down(sum, off, 64);
    if ((threadIdx.x & 63) == 0) red[threadIdx.x >> 6] = sum;
    __syncthreads();
    if (threadIdx.x == 0)
        blocksums[blockIdx.x] = (red[0] + red[1]) + (red[2] + red[3]);
}

// Pass 3: 256 block sums -> scalar loss.
__global__ __launch_bounds__(256) void final_kernel(
    const float* __restrict__ blocksums, float* __restrict__ out) {
    __shared__ float red[4];
    float v = blocksums[threadIdx.x];
#pragma unroll
    for (int off = 32; off; off >>= 1) v += __shfl_down(v, off, 64);
    if ((threadIdx.x & 63) == 0) red[threadIdx.x >> 6] = v;
    __syncthreads();
    if (threadIdx.x == 0)
        out[0] = ((red[0] + red[1]) + (red[2] + red[3])) * (2.0f / (float)TOTN);
}

extern "C" void kernel_launch(void* const* d_in, const int* in_sizes, int n_in,
                              void* d_out, int out_size, void* d_ws, size_t ws_size,
                              hipStream_t stream) {
    const float* xyz = (const float*)d_in[0];
    float* out = (float*)d_out;
    float* partial = (float*)d_ws;

    // Pick S (m-chunks) by available workspace: need S*TOTN+256 floats.
    int S;
    if (ws_size >= (size_t)(16 * TOTN + 256) * 4) S = 16;
    else if (ws_size >= (size_t)(4 * TOTN + 256) * 4) S = 4;
    else S = 1;
    float* blocksums = partial + (size_t)S * TOTN;

    const int nblocks = BATCH * 2 * S;
    switch (S) {
        case 16:
            chamfer_part_kernel<NPTS / 16><<<nblocks, 256, 0, stream>>>(xyz, partial);
            break;
        case 4:
            chamfer_part_kernel<NPTS / 4><<<nblocks, 256, 0, stream>>>(xyz, partial);
            break;
        default:
            chamfer_part_kernel<NPTS><<<nblocks, 256, 0, stream>>>(xyz, partial);
            break;
    }
    combine_kernel<<<TOTN / 256, 256, 0, stream>>>(xyz, partial, blocksums, S);
    final_kernel<<<1, 256, 0, stream>>>(blocksums, out);
}